// Round 5
// baseline (85.232 us; speedup 1.0000x reference)
//
#include <hip/hip_runtime.h>

#define N_FFT 1024
#define SPLIT0 513
// Swizzle in float2 units: pad 1 float2 every 16 (breaks pow-2 write strides).
#define PAD2(a) ((a) + ((a) >> 4))
#define PPB 4  // row-pairs (complex FFTs) per block

// Radix-4 Stockham, 5 passes. Pass 0 reads registers (loaded straight from
// global in natural order) and writes LDS; passes 1-4 are LDS->LDS; pass 4 is
// twiddle-free (jm==0). Buffer parity alternates per q so the untangle of q
// overlaps pass 0 of q+1 with no extra barrier. Next q's global loads issue
// right after pass 0 consumes the current registers.
__global__ __launch_bounds__(256) void rfft1024_pipe(const float* __restrict__ x,
                                                     float* __restrict__ out,
                                                     int nrows) {
    __shared__ float2 buf[2][N_FFT + 64];

    const int t = threadIdx.x;
    const int pair0 = blockIdx.x * PPB;

    float* __restrict__ outr = out;
    float* __restrict__ outi = out + (size_t)nrows * SPLIT0;

    // Load pair 0: z[r] = row0[t+256r] + i*row1[t+256r]; coalesced dword loads.
    float2 z[4];
    {
        const float* __restrict__ r0 = x + (size_t)(2 * pair0) * N_FFT;
        const float* __restrict__ r1 = r0 + N_FFT;
        #pragma unroll
        for (int r = 0; r < 4; ++r)
            z[r] = make_float2(r0[t + 256 * r], r1[t + 256 * r]);
    }

    #pragma unroll
    for (int q = 0; q < PPB; ++q) {
        const int par = q & 1;

        // ---- pass 0 (m=1, k=0, jm=t): registers -> buf[1^par]
        {
            float t0r = z[0].x + z[2].x, t0i = z[0].y + z[2].y;
            float t1r = z[0].x - z[2].x, t1i = z[0].y - z[2].y;
            float t2r = z[1].x + z[3].x, t2i = z[1].y + z[3].y;
            float t3r = z[1].x - z[3].x, t3i = z[1].y - z[3].y;
            float y0r = t0r + t2r, y0i = t0i + t2i;
            float y1r = t1r + t3i, y1i = t1i - t3r;  // t1 + (-i)*t3
            float y2r = t0r - t2r, y2i = t0i - t2i;
            float y3r = t1r - t3i, y3i = t1i + t3r;  // t1 - (-i)*t3
            float ph = (float)t * (-1.0f / 1024.0f);  // revolutions
            float c1 = __builtin_amdgcn_cosf(ph);
            float s1 = __builtin_amdgcn_sinf(ph);
            float c2 = c1 * c1 - s1 * s1, s2 = 2.0f * c1 * s1;
            float c3 = c1 * c2 - s1 * s2, s3 = c1 * s2 + s1 * c2;
            const int d = 1 ^ par;
            const int w0 = 4 * t;
            buf[d][PAD2(w0)]     = make_float2(y0r, y0i);
            buf[d][PAD2(w0 + 1)] = make_float2(y1r * c1 - y1i * s1, y1r * s1 + y1i * c1);
            buf[d][PAD2(w0 + 2)] = make_float2(y2r * c2 - y2i * s2, y2r * s2 + y2i * c2);
            buf[d][PAD2(w0 + 3)] = make_float2(y3r * c3 - y3i * s3, y3r * s3 + y3i * c3);
        }

        // Prefetch next pair's inputs; latency hidden behind passes 1-4.
        if (q + 1 < PPB) {
            const float* __restrict__ r0 = x + (size_t)(2 * (pair0 + q + 1)) * N_FFT;
            const float* __restrict__ r1 = r0 + N_FFT;
            #pragma unroll
            for (int r = 0; r < 4; ++r)
                z[r] = make_float2(r0[t + 256 * r], r1[t + 256 * r]);
        }
        __syncthreads();

        // ---- passes 1..3 (generic, with twiddles)
        #pragma unroll
        for (int p = 1; p <= 3; ++p) {
            const int m = 1 << (2 * p);
            const int k = t & (m - 1);
            const int jm = t - k;
            const int src = (p & 1) ^ par;
            const int dst = src ^ 1;

            float2 a = buf[src][PAD2(t)];
            float2 b = buf[src][PAD2(t + 256)];
            float2 c = buf[src][PAD2(t + 512)];
            float2 d = buf[src][PAD2(t + 768)];

            float t0r = a.x + c.x, t0i = a.y + c.y;
            float t1r = a.x - c.x, t1i = a.y - c.y;
            float t2r = b.x + d.x, t2i = b.y + d.y;
            float t3r = b.x - d.x, t3i = b.y - d.y;
            float y0r = t0r + t2r, y0i = t0i + t2i;
            float y1r = t1r + t3i, y1i = t1i - t3r;
            float y2r = t0r - t2r, y2i = t0i - t2i;
            float y3r = t1r - t3i, y3i = t1i + t3r;

            float ph = (float)jm * (-1.0f / 1024.0f);
            float c1 = __builtin_amdgcn_cosf(ph);
            float s1 = __builtin_amdgcn_sinf(ph);
            float c2 = c1 * c1 - s1 * s1, s2 = 2.0f * c1 * s1;
            float c3 = c1 * c2 - s1 * s2, s3 = c1 * s2 + s1 * c2;

            const int w0 = k + 4 * jm;
            buf[dst][PAD2(w0)]         = make_float2(y0r, y0i);
            buf[dst][PAD2(w0 + m)]     = make_float2(y1r * c1 - y1i * s1, y1r * s1 + y1i * c1);
            buf[dst][PAD2(w0 + 2 * m)] = make_float2(y2r * c2 - y2i * s2, y2r * s2 + y2i * c2);
            buf[dst][PAD2(w0 + 3 * m)] = make_float2(y3r * c3 - y3i * s3, y3r * s3 + y3i * c3);
            __syncthreads();
        }

        // ---- pass 4 (m=256 -> jm=0, twiddle-free). Reads/writes at t+256r.
        {
            const int src = 0 ^ par;
            const int dst = src ^ 1;
            float2 a = buf[src][PAD2(t)];
            float2 b = buf[src][PAD2(t + 256)];
            float2 c = buf[src][PAD2(t + 512)];
            float2 d = buf[src][PAD2(t + 768)];

            float t0r = a.x + c.x, t0i = a.y + c.y;
            float t1r = a.x - c.x, t1i = a.y - c.y;
            float t2r = b.x + d.x, t2i = b.y + d.y;
            float t3r = b.x - d.x, t3i = b.y - d.y;

            buf[dst][PAD2(t)]       = make_float2(t0r + t2r, t0i + t2i);
            buf[dst][PAD2(t + 256)] = make_float2(t1r + t3i, t1i - t3r);
            buf[dst][PAD2(t + 512)] = make_float2(t0r - t2r, t0i - t2i);
            buf[dst][PAD2(t + 768)] = make_float2(t1r - t3i, t1i + t3r);
            __syncthreads();
        }

        // ---- untangle from buf[1^par] and store; overlaps next q's pass 0.
        // X0[k] = (Z[k]+conj(Z[N-k]))/2 ; X1[k] = -i/2*(Z[k]-conj(Z[N-k])).
        {
            const int bsel = 1 ^ par;
            const size_t row0 = (size_t)(2 * (pair0 + q));
            #pragma unroll
            for (int c = 0; c < 2; ++c) {
                int kk = t + 256 * c;
                float2 zz = buf[bsel][PAD2(kk)];
                int km = (N_FFT - kk) & (N_FFT - 1);
                float2 zm = buf[bsel][PAD2(km)];
                float X0r = 0.5f * (zz.x + zm.x), X0i = 0.5f * (zz.y - zm.y);
                float X1r = 0.5f * (zz.y + zm.y), X1i = 0.5f * (zm.x - zz.x);
                outr[row0 * SPLIT0 + kk]       = X0r;
                outi[row0 * SPLIT0 + kk]       = X0i;
                outr[(row0 + 1) * SPLIT0 + kk] = X1r;
                outi[(row0 + 1) * SPLIT0 + kk] = X1i;
            }
            if (t == 0) {
                float2 zz = buf[bsel][PAD2(512)];
                outr[row0 * SPLIT0 + 512]       = zz.x;
                outi[row0 * SPLIT0 + 512]       = 0.0f;
                outr[(row0 + 1) * SPLIT0 + 512] = zz.y;
                outi[(row0 + 1) * SPLIT0 + 512] = 0.0f;
            }
        }
        // No trailing barrier: next q's pass 0 writes buf[par] (disjoint from
        // buf[1^par] read here), and its pass-1 write of buf[1^par] is fenced
        // by the barrier that follows pass 0.
    }
}

extern "C" void kernel_launch(void* const* d_in, const int* in_sizes, int n_in,
                              void* d_out, int out_size, void* d_ws, size_t ws_size,
                              hipStream_t stream) {
    const float* x = (const float*)d_in[0];
    float* out = (float*)d_out;
    const int nrows = in_sizes[0] / N_FFT;  // 8192
    const int npairs = nrows / 2;           // 4096
    rfft1024_pipe<<<npairs / PPB, 256, 0, stream>>>(x, out, nrows);
}